// Round 1
// baseline (411.863 us; speedup 1.0000x reference)
//
#include <hip/hip_runtime.h>
#include <stdint.h>

// out[b,o] = sum_i W[i,o] * I[i,b],  I = per-object concat [first|mid0|mid1|last].
// ROWS = 17408 = 136 blocks of 128 rows; each 128-row block lies in one segment.
//
// R4 lesson: VGPR global-load path capped at ~1.75 TB/s (waitcnt-serialized).
// R5 (prev): global_load_lds DMA double-buffer -> ~2.7 TB/s effective, but
// __syncthreads drains vmcnt(0) every stage (burst-then-drain duty cycle).
// R6 (this): T3+T4 counted-vmcnt pipeline. Depth-3 LDS ring, raw s_barrier,
// s_waitcnt vmcnt(4) in steady state -- prefetched DMAs stay in flight ACROSS
// barriers (m218: counted-vs-drain0 = +38..73% on GEMM; same mechanism here).
// LDS = 16KB weights + 3x16KB x ring = 64 KB static -> 2 blocks/CU, 8 waves/CU.
// Per-wave outstanding DMA = 8 (two stages); never drains to 0 until the tail.
// Fixed harness overhead (1 GiB ws poison + input restore) ~= 260 us of dur_us.

#define BATCH  4096
#define OUTC   32
#define NCHUNK 136     // one 128-row block per chunk; ws = 71.3 MB
#define BTILES 8       // 8 b-tiles x 512 b
#define RSTAGE 8       // rows per pipeline stage (16 KB / stage)
#define NSTAGE 16      // 128 / RSTAGE
#define NBUF   3       // x ring depth

// DMA one 16B/lane wave-copy: 64 lanes * 16 B = 1024 B contiguous into LDS at
// a wave-uniform base (global_load_lds semantics: dst = base + lane*16).
__device__ __forceinline__ void dma16(const float* g, float* l) {
    __builtin_amdgcn_global_load_lds(
        (const __attribute__((address_space(1))) void*)g,
        (__attribute__((address_space(3))) void*)l, 16, 0, 0);
}

// Block = 256 thr = 4 waves (bsub x ohalf) over a 512b x 128row tile.
// Thread: 4 consecutive b x 16 outs -> 64 accumulators.
__global__ __launch_bounds__(256, 2) void cwl_partial(
    const float* __restrict__ cf,   // (4,128,4096)
    const float* __restrict__ cm,   // (4,2,2048,4096)
    const float* __restrict__ cl,   // (4,128,4096)
    const float* __restrict__ w,    // (17408,32)
    float* __restrict__ ws)         // (NCHUNK,4096,32)
{
    __shared__ float wlds[128 * OUTC];            // 16 KB: this block's weights
    __shared__ float xlds[NBUF][RSTAGE * 512];    // 3 x 16 KB: x ring

    const int chunk = blockIdx.x % NCHUNK;        // row-block 0..135
    const int btile = blockIdx.x / NCHUNK;
    const int tid   = threadIdx.x;
    const int wv    = tid >> 6;
    const int lane  = tid & 63;
    const int ohalf = wv & 1;
    const int bsub  = wv >> 1;

    const int c = chunk / 34;
    const int j = chunk % 34;
    const float* src = (j == 0)  ? cf + (size_t)c * 128 * BATCH
                     : (j == 33) ? cl + (size_t)c * 128 * BATCH
                     : cm + ((size_t)c * 4096 + (size_t)(j - 1) * 128) * BATCH;
    const float* srcg = src + btile * 512;                  // block's b-slice
    const float* wg   = w + (size_t)chunk * 128 * OUTC;     // 4096 floats

    // ---- prologue: weights (4 dma/wave) + stage 0 + stage 1 (4 dma/wave each)
    // outstanding per wave after prologue: 12.
#pragma unroll
    for (int t = 0; t < 4; ++t) {
        const int seg = wv * 4 + t;                          // 0..15
        dma16(wg + seg * 256 + lane * 4, wlds + seg * 256);
    }
#pragma unroll
    for (int t = 0; t < 4; ++t) {
        const int row  = wv * 2 + (t >> 1);                  // 0..7
        const int half = t & 1;
        dma16(srcg + (size_t)row * BATCH + half * 256 + lane * 4,
              &xlds[0][row * 512 + half * 256]);
    }
#pragma unroll
    for (int t = 0; t < 4; ++t) {
        const int row  = wv * 2 + (t >> 1);
        const int half = t & 1;
        dma16(srcg + (size_t)(RSTAGE + row) * BATCH + half * 256 + lane * 4,
              &xlds[1][row * 512 + half * 256]);
    }

    float acc[16][4];
#pragma unroll
    for (int o = 0; o < 16; ++o)
#pragma unroll
        for (int bi = 0; bi < 4; ++bi) acc[o][bi] = 0.0f;

    const int xoff = bsub * 256 + lane * 4;   // thread's float4 within a row

    for (int s = 0; s < NSTAGE; ++s) {
        // Wait until stage s is resident. Steady state: stage s+1 (4 DMAs/wave)
        // stays IN FLIGHT across the barrier (counted vmcnt, never drain-0
        // until the last stage). At s==0 this also covers the weights DMA:
        // outstanding = {W:4, s0:4, s1:4}; vmcnt(4) leaves only s1 pending.
        if (s + 1 < NSTAGE) {
            asm volatile("s_waitcnt vmcnt(4)" ::: "memory");
        } else {
            asm volatile("s_waitcnt vmcnt(0)" ::: "memory");
        }
        __builtin_amdgcn_s_barrier();          // all waves have stage s in LDS
        __builtin_amdgcn_sched_barrier(0);     // fence: no ds_read hoisted above

        // Issue DMA for stage s+2 into the ring slot freed by stage s-1
        // (the barrier above guarantees every wave finished computing s-1).
        if (s + 2 < NSTAGE) {
            float* xn = xlds[(s + 2) % NBUF];
            const int r0 = (s + 2) * RSTAGE;
#pragma unroll
            for (int t = 0; t < 4; ++t) {
                const int row  = wv * 2 + (t >> 1);
                const int half = t & 1;
                dma16(srcg + (size_t)(r0 + row) * BATCH + half * 256 + lane * 4,
                      xn + row * 512 + half * 256);
            }
        }

        const float* xb   = xlds[s % NBUF];
        const float* wrow = wlds + s * RSTAGE * OUTC + ohalf * 16;
#pragma unroll
        for (int r = 0; r < RSTAGE; ++r) {
            const float4 x = *(const float4*)(xb + r * 512 + xoff);
            const float4* wr = (const float4*)(wrow + r * OUTC);
#pragma unroll
            for (int q = 0; q < 4; ++q) {
                const float4 wq = wr[q];     // wave-uniform LDS broadcast
#pragma unroll
                for (int jj = 0; jj < 4; ++jj) {
                    const float wj = ((const float*)&wq)[jj];
                    const int o = q * 4 + jj;
                    acc[o][0] = fmaf(x.x, wj, acc[o][0]);
                    acc[o][1] = fmaf(x.y, wj, acc[o][1]);
                    acc[o][2] = fmaf(x.z, wj, acc[o][2]);
                    acc[o][3] = fmaf(x.w, wj, acc[o][3]);
                }
            }
        }
        // No trailing barrier: the next iteration's vmcnt+s_barrier both
        // publishes stage s+1 and protects the ring slot being overwritten.
    }

    // ws[chunk][b][o]: 16 floats per (thread, bi) -> coalesced float4 stores.
    const int b0 = btile * 512 + bsub * 256 + lane * 4;
#pragma unroll
    for (int bi = 0; bi < 4; ++bi) {
        float4* dst = (float4*)(ws + ((size_t)chunk * BATCH + (b0 + bi)) * OUTC
                                + ohalf * 16);
#pragma unroll
        for (int q = 0; q < 4; ++q)
            dst[q] = make_float4(acc[q*4+0][bi], acc[q*4+1][bi],
                                 acc[q*4+2][bi], acc[q*4+3][bi]);
    }
}

// out[t] = sum_c ws[c][t]; 4 independent chains, fully coalesced.
__global__ __launch_bounds__(256) void cwl_reduce(
    const float* __restrict__ ws, float* __restrict__ out)
{
    const int t = blockIdx.x * 256 + threadIdx.x;   // 0..131071
    float s0 = 0.f, s1 = 0.f, s2 = 0.f, s3 = 0.f;
#pragma unroll 4
    for (int c = 0; c < NCHUNK; c += 4) {
        s0 += ws[(size_t)(c+0) * (BATCH * OUTC) + t];
        s1 += ws[(size_t)(c+1) * (BATCH * OUTC) + t];
        s2 += ws[(size_t)(c+2) * (BATCH * OUTC) + t];
        s3 += ws[(size_t)(c+3) * (BATCH * OUTC) + t];
    }
    out[t] = (s0 + s1) + (s2 + s3);
}

extern "C" void kernel_launch(void* const* d_in, const int* in_sizes, int n_in,
                              void* d_out, int out_size, void* d_ws, size_t ws_size,
                              hipStream_t stream)
{
    const float* cf = (const float*)d_in[0];
    const float* cm = (const float*)d_in[1];
    const float* cl = (const float*)d_in[2];
    const float* w  = (const float*)d_in[3];
    float* out = (float*)d_out;
    float* ws  = (float*)d_ws;   // 136*131072*4 = 71.3 MB used

    cwl_partial<<<dim3(NCHUNK * BTILES), dim3(256), 0, stream>>>(cf, cm, cl, w, ws);
    cwl_reduce<<<dim3((BATCH * OUTC) / 256), dim3(256), 0, stream>>>(ws, out);
}